// Round 21
// baseline (53.575 us; speedup 1.0000x reference)
//
#include <hip/hip_runtime.h>
#include <hip/hip_bf16.h>

// ---------------------------------------------------------------------------
// SingleHead attention: q=xWq, k=xWk, v=xWv; causal softmax(qk^T/sqrt(64)) v
// B=8, T=2048, C=1024, D=64.  Output fp32 [B,T,64].
//
//   k0: WT bf16 transpose of [Wq|Wk|Wv] (192x1024), pre-swizzled tile layout,
//       0.125*log2(e) folded into q columns.  LDS-transpose, coalesced 16B
//       writes.
//   k1: QKV projection GEMM, 32 tok x 192 ft block, K-step 64, dbuf LDS,
//       x reg-prefetch depth 2, WT via global_load_lds, XCD-affine grid
//   k2: split-K flash attn partials, swapped QK^T, K/V LDS dbuf,
//       id%8==batch XCD mapping; po partials in BF16; MAXCH=8.
//       v2: COMPACTED triangular grid (1152 blocks, no empty dispatches).
//   k3: combine partials, 512 blocks (2 per q-tile, 32 rows each),
//       static unroll 8, bf16 po reads, fp32 accumulate
//
//   Measured landscape (20 rounds): MAXCH {4,8,16} -> {60.4, 53.7, 56.6};
//   fused-combine via threadfence = +160us; nontemporal po = +4.5us;
//   direct-L2 K/V = +25us; 8-wave block = +2us.  Champion: 53.33us.
// ---------------------------------------------------------------------------

typedef __attribute__((ext_vector_type(8))) short short8;   // 8 x bf16 frag
typedef __attribute__((ext_vector_type(4))) float f32x4;    // C/D frag

#define MFMA16(a, b, c) __builtin_amdgcn_mfma_f32_16x16x32_bf16((a), (b), (c), 0, 0, 0)

__device__ __forceinline__ unsigned short f2bf(float f) {
  unsigned int u = __builtin_bit_cast(unsigned int, f);
  unsigned int r = 0x7fffu + ((u >> 16) & 1u);
  return (unsigned short)((u + r) >> 16);
}
__device__ __forceinline__ float bf2f(unsigned short h) {
  unsigned int u = ((unsigned int)h) << 16;
  return __builtin_bit_cast(float, u);
}

#define BATCH 8
#define SEQ   2048
#define CDIM  1024
#define DDIM  64
#define NTOK  (BATCH * SEQ)   // 16384
#define LOG2E 1.44269504f

// ---------------------------------------------------------------------------
// Kernel 0: WT pre-swizzled tiles via LDS transpose.
//   Grid 48 = 3 W x 16 k-steps; block 256.  Tile = 64 k x 64 c fp32.
//   Layout: WT[step*12288 + row*64 + ((col>>3)^(row&7))*8 + (col&7)]
// ---------------------------------------------------------------------------
__global__ __launch_bounds__(256) void wt_kernel(const float* __restrict__ Wq,
                                                 const float* __restrict__ Wk,
                                                 const float* __restrict__ Wv,
                                                 unsigned short* __restrict__ WT) {
  __shared__ float tile[64 * 68];                 // [k_local][c], stride 68
  const int wi   = blockIdx.x >> 4;               // 0..2
  const int step = blockIdx.x & 15;               // 0..15
  const int tid  = threadIdx.x;
  const float* W = (wi == 0) ? Wq : ((wi == 1) ? Wk : Wv);
  const float scale = (wi == 0) ? 0.125f * LOG2E : 1.0f;

#pragma unroll
  for (int j = 0; j < 4; ++j) {
    int r  = j * 16 + (tid >> 4);                 // k_local 0..63
    int cq = (tid & 15) * 4;                      // col quad
    f32x4 v = *reinterpret_cast<const f32x4*>(W + (size_t)(step * 64 + r) * 64 + cq);
    v *= scale;
    *reinterpret_cast<f32x4*>(&tile[r * 68 + cq]) = v;
  }
  __syncthreads();

#pragma unroll
  for (int u = 0; u < 2; ++u) {
    int p  = tid * 2 + u;                         // chunk id 0..511
    int c  = p >> 3;                              // output row within W (0..63)
    int j  = p & 7;                               // output chunk
    int k0 = (j ^ (c & 7)) * 8;                   // source col base
    short8 h;
#pragma unroll
    for (int e = 0; e < 8; ++e)
      h[e] = (short)f2bf(tile[(k0 + e) * 68 + c]);
    *reinterpret_cast<short8*>(
        WT + (size_t)step * 12288 + (size_t)(wi * 64 + c) * 64 + j * 8) = h;
  }
}

// ---------------------------------------------------------------------------
// Kernel 1: fused QKV projection GEMM.
//   512 thr = 8 waves (2M x 4N). Block tile 32 tok x 192 ft. K-step 64.
//   x register-prefetched 2 steps ahead; WT LDS-dbuf via global_load_lds.
//   XCD-affine: n0 = (id&7)*2048 + (id>>3)*32  (id%8 == batch == XCD).
// ---------------------------------------------------------------------------
__global__ __launch_bounds__(512) void proj_kernel(const float* __restrict__ x,
                                                   const unsigned short* __restrict__ WT,
                                                   unsigned short* __restrict__ qws,
                                                   unsigned short* __restrict__ kws,
                                                   unsigned short* __restrict__ vtws) {
  __shared__ __align__(16) unsigned short xs[2][32 * 64];    // 4KB each
  __shared__ __align__(16) unsigned short wl[2][192 * 64];   // 24KB each

  const int tid  = threadIdx.x;
  const int lane = tid & 63;
  const int w    = tid >> 6;       // 0..7
  const int wm   = w & 1;          // M half (16 tok)
  const int wn   = w >> 1;         // N quarter (48 ft)
  const int c16  = lane & 15;
  const int hi   = lane >> 4;
  const int id   = blockIdx.x;
  const int n0   = (id & 7) * SEQ + (id >> 3) * 32;   // XCD-affine token base
  const bool xldr = (tid < 256);
  const int trow = (tid >> 3) & 31;  // 0..31 (x staging row, tid<256)
  const int kch  = tid & 7;          // 0..7  (x staging 16B chunk)

  f32x4 acc[3];
#pragma unroll
  for (int ct = 0; ct < 3; ++ct) acc[ct] = (f32x4){0.f, 0.f, 0.f, 0.f};

  const float* xbase = x + (size_t)(n0 + trow) * CDIM + kch * 8;
  const int xsw = trow * 64 + ((kch ^ (trow & 7)) * 8);   // swizzled x slot

  const unsigned short* wsrc = WT + (size_t)w * 1536 + (size_t)lane * 8;
  auto stage_wt = [&](int step, int bufi) {
    const unsigned short* s = wsrc + (size_t)step * 12288;
    unsigned short* d = &wl[bufi][w * 1536];
#pragma unroll
    for (int j = 0; j < 3; ++j)
      __builtin_amdgcn_global_load_lds(
          (const __attribute__((address_space(1))) void*)(s + j * 512),
          (__attribute__((address_space(3))) void*)(d + j * 512), 16, 0, 0);
  };
  auto xstore = [&](f32x4 a, f32x4 b, int bufi) {
    short8 h;
#pragma unroll
    for (int j = 0; j < 4; ++j) { h[j] = (short)f2bf(a[j]); h[4 + j] = (short)f2bf(b[j]); }
    *reinterpret_cast<short8*>(&xs[bufi][xsw]) = h;
  };

  // ---- prologue ----
  f32x4 xa1 = {0,0,0,0}, xb1 = xa1, xa2 = xa1, xb2 = xa1;
  if (xldr) {
    f32x4 a0 = *reinterpret_cast<const f32x4*>(xbase);
    f32x4 b0 = *reinterpret_cast<const f32x4*>(xbase + 4);
    xstore(a0, b0, 0);
    xa1 = *reinterpret_cast<const f32x4*>(xbase + 64);
    xb1 = *reinterpret_cast<const f32x4*>(xbase + 64 + 4);
  }
  stage_wt(0, 0);
  __syncthreads();

  int cur = 0;
  for (int st = 0; st < 16; ++st) {
    if (st + 2 < 16 && xldr) {
      xa2 = *reinterpret_cast<const f32x4*>(xbase + (st + 2) * 64);
      xb2 = *reinterpret_cast<const f32x4*>(xbase + (st + 2) * 64 + 4);
    }
    if (st + 1 < 16) stage_wt(st + 1, cur ^ 1);

    // ---- compute on cur ----
    short8 bfrag[2];
    {
      int r = wm * 16 + c16;
#pragma unroll
      for (int f = 0; f < 2; ++f)
        bfrag[f] = *reinterpret_cast<const short8*>(
            &xs[cur][r * 64 + (((f * 4 + hi) ^ (r & 7)) * 8)]);
    }
#pragma unroll
    for (int ct = 0; ct < 3; ++ct) {
      int ra = (wn * 3 + ct) * 16 + c16;
#pragma unroll
      for (int f = 0; f < 2; ++f) {
        short8 af = *reinterpret_cast<const short8*>(
            &wl[cur][ra * 64 + (((f * 4 + hi) ^ (ra & 7)) * 8)]);
        acc[ct] = MFMA16(af, bfrag[f], acc[ct]);
      }
    }

    if (st + 1 < 16 && xldr) xstore(xa1, xb1, cur ^ 1);
    __syncthreads();
    xa1 = xa2; xb1 = xb2;
    cur ^= 1;
  }

  // ---- epilogue: lane holds D[feat = (wn*3+ct)*16+hi*4+r][token] ----
  {
    const int token = n0 + wm * 16 + c16;
    const int b = token >> 11;
    const int t = token & 2047;
#pragma unroll
    for (int ct = 0; ct < 3; ++ct) {
      int cg = (wn * 3 + ct) * 16 + hi * 4;
      unsigned short h[4];
#pragma unroll
      for (int r = 0; r < 4; ++r) h[r] = f2bf(acc[ct][r]);
      if (cg < 64) {
        *reinterpret_cast<ushort4*>(qws + (size_t)token * DDIM + cg) =
            make_ushort4(h[0], h[1], h[2], h[3]);
      } else if (cg < 128) {
        *reinterpret_cast<ushort4*>(kws + (size_t)token * DDIM + (cg - 64)) =
            make_ushort4(h[0], h[1], h[2], h[3]);
      } else {
        int cv = cg - 128;
#pragma unroll
        for (int r = 0; r < 4; ++r)
          vtws[(size_t)(b * DDIM + cv + r) * SEQ + t] = h[r];
      }
    }
  }
}

// ---------------------------------------------------------------------------
// Kernel 2: split-K flash attention partials, swapped-QK^T, K/V dbuf.
//   v2 COMPACTED grid: id&7 = batch (XCD-local); a = id>>3 indexes only
//   ACTIVE (qt,ch) pairs.  nch(qt) = qt/TPC + 1 (TPC = 32/MAXCH tiles per
//   chunk); group g has TPC q-tiles of g+1 chunks, prefix P(g)=TPC*g(g+1)/2;
//   qt = g*TPC + rem/(g+1), ch = rem%(g+1).
//   256 thr = 4 waves; wave = 16 q rows; lane owns q = qr0 + (lane&15).
//   P^T per wave in chunk-major LDS.  LDS = 40KB.  po partials BF16.
// ---------------------------------------------------------------------------
__global__ __launch_bounds__(256) void attn_partial(const unsigned short* __restrict__ qws,
                                                    const unsigned short* __restrict__ kws,
                                                    const unsigned short* __restrict__ vtws,
                                                    unsigned short* __restrict__ po,
                                                    float* __restrict__ pml,
                                                    int MAXCH, int CHUNK) {
  __shared__ __align__(16) unsigned short kt[2][64 * 64];   // K tile  [kv][d]
  __shared__ __align__(16) unsigned short vt[2][64 * 64];   // V^T tile [dv][kv]
  __shared__ __align__(16) unsigned short pt[4][1024];      // P^T chunk-major

  const int id = blockIdx.x;
  const int b  = id & 7;
  const int a  = id >> 3;                 // compact active-pair index
  const int TPC = 32 / MAXCH;             // 64-row tiles per chunk

  int g = 0, Pg = 0;
  for (int h = 1; h < MAXCH; ++h) {       // find group: largest h, P(h)<=a
    int Ph = TPC * h * (h + 1) / 2;
    if (Ph <= a) { g = h; Pg = Ph; } else break;
  }
  const int rem = a - Pg;
  const int qt  = g * TPC + rem / (g + 1);
  const int ch  = rem % (g + 1);

  const int kv_end = qt * 64 + 64;
  const int kv0_ch = ch * CHUNK;
  if (kv0_ch >= kv_end) return;           // defensive (never taken)
  const int block_lim = min(kv0_ch + CHUNK, kv_end);
  const int nt = (block_lim - kv0_ch + 63) >> 6;

  const int tid  = threadIdx.x;
  const int lane = tid & 63;
  const int w    = tid >> 6;
  const int c    = lane & 15;
  const int hi   = lane >> 4;
  const int qr0  = qt * 64 + w * 16;
  const int q    = qr0 + c;            // this lane's q row
  const int kv_last = qr0 + 15;        // wave causal limit

  const unsigned short* qb = qws + (size_t)b * SEQ * DDIM;
  short8 aq0 = *reinterpret_cast<const short8*>(qb + (size_t)q * DDIM + hi * 8);
  short8 aq1 = *reinterpret_cast<const short8*>(qb + (size_t)q * DDIM + 32 + hi * 8);

  float m = -INFINITY, l = 0.f;
  f32x4 o[4];
#pragma unroll
  for (int dn = 0; dn < 4; ++dn) o[dn] = (f32x4){0.f, 0.f, 0.f, 0.f};

  unsigned short* pwv = pt[w];
  const unsigned short* kb = kws + (size_t)b * SEQ * DDIM;
  const unsigned short* vb = vtws + (size_t)b * DDIM * SEQ;

  auto stage_kv = [&](int bufi, int kv0) {   // 4 vm ops per wave
#pragma unroll
    for (int j = 0; j < 2; ++j) {
      int p   = w * 128 + j * 64 + lane;   // 16B chunk index 0..511
      int row = p >> 3;
      int chk = (p & 7) ^ (row & 7);
      __builtin_amdgcn_global_load_lds(
          (const __attribute__((address_space(1))) void*)(kb + (size_t)(kv0 + row) * DDIM + chk * 8),
          (__attribute__((address_space(3))) void*)(&kt[bufi][w * 1024 + j * 512]), 16, 0, 0);
      __builtin_amdgcn_global_load_lds(
          (const __attribute__((address_space(1))) void*)(vb + (size_t)row * SEQ + kv0 + chk * 8),
          (__attribute__((address_space(3))) void*)(&vt[bufi][w * 1024 + j * 512]), 16, 0, 0);
    }
  };

  // ---- prologue ----
  stage_kv(0, kv0_ch);
  asm volatile("s_waitcnt vmcnt(0)" ::: "memory");
  __builtin_amdgcn_s_barrier();

  int cur = 0;
  for (int t = 0; t < nt; ++t) {
    const int kv0 = kv0_ch + t * 64;
    if (t + 1 < nt) stage_kv(cur ^ 1, kv0 + 64);   // issue-early, drain at end

    if (kv0 <= kv_last) {
      // ---- S^T = K q^T : lane holds S^T[kv = n*16+hi*4+r][q=c] ----
      f32x4 s[4];
#pragma unroll
      for (int n = 0; n < 4; ++n) {
        if (kv0 + n * 16 > kv_last) {
          s[n] = (f32x4){-INFINITY, -INFINITY, -INFINITY, -INFINITY};
          continue;
        }
        const unsigned short* kr = &kt[cur][(n * 16 + c) * 64];
        short8 ka0 = *reinterpret_cast<const short8*>(kr + ((hi ^ (c & 7)) * 8));
        short8 ka1 = *reinterpret_cast<const short8*>(kr + (((4 + hi) ^ (c & 7)) * 8));
        f32x4 z = (f32x4){0.f, 0.f, 0.f, 0.f};
        z = MFMA16(ka0, aq0, z);
        s[n] = MFMA16(ka1, aq1, z);
      }

      // ---- causal mask (near diagonal only) ----
      if (kv0 + 63 > qr0) {
#pragma unroll
        for (int n = 0; n < 4; ++n)
#pragma unroll
          for (int r = 0; r < 4; ++r)
            if (kv0 + n * 16 + hi * 4 + r > q) s[n][r] = -INFINITY;
      }

      // ---- online softmax (exp2 domain; state lane-local) ----
      float mx = -INFINITY;
#pragma unroll
      for (int n = 0; n < 4; ++n)
        mx = fmaxf(mx, fmaxf(fmaxf(s[n][0], s[n][1]), fmaxf(s[n][2], s[n][3])));
      mx = fmaxf(mx, __shfl_xor(mx, 16, 64));
      mx = fmaxf(mx, __shfl_xor(mx, 32, 64));

      float nm = fmaxf(m, mx);
      float sc = __builtin_exp2f(m - nm);
      m = nm;

      // ---- P = exp2(S - nm); write P^T chunk-major (4 x ds_write_b64) ----
      float ssum = 0.f;
#pragma unroll
      for (int n = 0; n < 4; ++n) {
        float pv0 = __builtin_exp2f(s[n][0] - nm);
        float pv1 = __builtin_exp2f(s[n][1] - nm);
        float pv2 = __builtin_exp2f(s[n][2] - nm);
        float pv3 = __builtin_exp2f(s[n][3] - nm);
        ssum += (pv0 + pv1) + (pv2 + pv3);
        ushort4 h4 = make_ushort4(f2bf(pv0), f2bf(pv1), f2bf(pv2), f2bf(pv3));
        *reinterpret_cast<ushort4*>(
            pwv + (2 * n + (hi >> 1)) * 128 + c * 8 + (hi & 1) * 4) = h4;
      }
      ssum += __shfl_xor(ssum, 16, 64);
      ssum += __shfl_xor(ssum, 32, 64);
      l = l * sc + ssum;

#pragma unroll
      for (int dn = 0; dn < 4; ++dn) o[dn] *= sc;

      // ---- O^T += V^T P^T  (bp: 1 x ds_read_b128 per f) ----
      const int nf = (kv0 + 32 <= kv_last) ? 2 : 1;
      for (int f = 0; f < nf; ++f) {
        short8 bp = *reinterpret_cast<const short8*>(pwv + (f * 4 + hi) * 128 + c * 8);
#pragma unroll
        for (int dn = 0; dn < 4; ++dn) {
          const unsigned short* vr = &vt[cur][(dn * 16 + c) * 64];
          short8 va = *reinterpret_cast<const short8*>(vr + (((f * 4 + hi) ^ (c & 7)) * 8));
          o[dn] = MFMA16(va, bp, o[dn]);
        }
      }
    }

    if (t + 1 < nt) {
      asm volatile("s_waitcnt vmcnt(0)" ::: "memory");   // next tile staged
      __builtin_amdgcn_s_barrier();
    }
    cur ^= 1;
  }

  // ---- write partials (BF16): po [q-in-tile][dv], dv = dn*16+hi*4+r ----
  unsigned short* pob =
      po + (((size_t)(b * 32 + qt) * MAXCH + ch) * 64 + w * 16 + c) * 64 + hi * 4;
#pragma unroll
  for (int dn = 0; dn < 4; ++dn) {
    ushort4 h4 = make_ushort4(f2bf(o[dn][0]), f2bf(o[dn][1]),
                              f2bf(o[dn][2]), f2bf(o[dn][3]));
    *reinterpret_cast<ushort4*>(pob + dn * 16) = h4;
  }

  if (hi == 0) {
    *reinterpret_cast<float2*>(
        pml + (((size_t)(b * 32 + qt) * MAXCH + ch) * 64 + w * 16 + c) * 2) =
        make_float2(m, l);
  }
}

// ---------------------------------------------------------------------------
// Kernel 3: combine partials.  512 blocks = 2 per (b,qt), 32 rows each;
//   id%8 = batch (XCD-local po reads).  256 thr; 8 thr/row, one short8/chunk.
// ---------------------------------------------------------------------------
__global__ __launch_bounds__(256) void attn_combine(const unsigned short* __restrict__ po,
                                                    const float* __restrict__ pml,
                                                    float* __restrict__ out,
                                                    int MAXCH, int CHUNK) {
  const int id   = blockIdx.x;
  const int b    = id & 7;
  const int q2   = id >> 3;            // 0..63
  const int qt   = q2 >> 1;
  const int half = q2 & 1;
  const int tid  = threadIdx.x;
  const int row  = half * 32 + (tid >> 3);   // 0..63 within tile
  const int g    = tid & 7;                  // 8-feature group
  const int nch  = min((qt * 64 + 64 + CHUNK - 1) / CHUNK, MAXCH);

  const size_t base = (size_t)(b * 32 + qt) * MAXCH;

  float mv0 = -INFINITY, mv1 = -INFINITY, mv2 = -INFINITY, mv3 = -INFINITY;
  float mv4 = -INFINITY, mv5 = -INFINITY, mv6 = -INFINITY, mv7 = -INFINITY;
  float lv0 = 0, lv1 = 0, lv2 = 0, lv3 = 0, lv4 = 0, lv5 = 0, lv6 = 0, lv7 = 0;
#define LOADML(i) if (i < nch) { \
    float2 t = *reinterpret_cast<const float2*>(pml + (base + i) * 128 + row * 2); \
    mv##i = t.x; lv##i = t.y; }
  LOADML(0) LOADML(1) LOADML(2) LOADML(3) LOADML(4) LOADML(5) LOADML(6) LOADML(7)
#undef LOADML

  float M = fmaxf(fmaxf(fmaxf(mv0, mv1), fmaxf(mv2, mv3)),
                  fmaxf(fmaxf(mv4, mv5), fmaxf(mv6, mv7)));

  float L = 0.f;
  f32x4 a0 = {0.f,0.f,0.f,0.f}, a1 = a0;
#define ACC(i) if (i < nch) { \
    float wgt = __builtin_exp2f(mv##i - M); \
    L += wgt * lv##i; \
    const unsigned short* p = po + (base + i) * 4096 + row * 64 + g * 8; \
    short8 v0 = *reinterpret_cast<const short8*>(p); \
    f32x4 t0, t1; \
    for (int j = 0; j < 4; ++j) { \
      t0[j] = bf2f((unsigned short)v0[j]); \
      t1[j] = bf2f((unsigned short)v0[4 + j]); \
    } \
    a0 += wgt * t0; a1 += wgt * t1; }
  ACC(0) ACC(1) ACC(2) ACC(3) ACC(4) ACC(5) ACC(6) ACC(7)
#undef ACC

  float invL = 1.f / L;
  float* ob = out + ((size_t)b * SEQ + qt * 64 + row) * 64 + g * 8;
  *reinterpret_cast<f32x4*>(ob)     = a0 * invL;
  *reinterpret_cast<f32x4*>(ob + 4) = a1 * invL;
}

// ---------------------------------------------------------------------------
extern "C" void kernel_launch(void* const* d_in, const int* in_sizes, int n_in,
                              void* d_out, int out_size, void* d_ws, size_t ws_size,
                              hipStream_t stream) {
  const float* x  = (const float*)d_in[0];
  const float* Wq = (const float*)d_in[1];
  const float* Wk = (const float*)d_in[2];
  const float* Wv = (const float*)d_in[3];
  float* out = (float*)d_out;

  unsigned short* qws  = (unsigned short*)d_ws;            // 2MB
  unsigned short* kws  = qws + (size_t)NTOK * DDIM;        // 2MB
  unsigned short* vtws = kws + (size_t)NTOK * DDIM;        // 2MB
  unsigned short* WT   = vtws + (size_t)NTOK * DDIM;       // 384KB
  size_t fixed_end = (size_t)NTOK * DDIM * 3 * 2 + 192 * 1024 * 2;

  int MAXCH = 1;
  {
    const int cand[4] = {8, 4, 2, 1};
    for (int i = 0; i < 4; ++i) {
      size_t need = fixed_end +
                    (size_t)cand[i] * (8ull * 32 * 64 * 64 * 2 + 8ull * 32 * 64 * 2 * 4);
      if (need <= ws_size) { MAXCH = cand[i]; break; }
    }
  }

  wt_kernel<<<48, 256, 0, stream>>>(Wq, Wk, Wv, WT);
  proj_kernel<<<NTOK / 32, 512, 0, stream>>>(x, WT, qws, kws, vtws);

  unsigned short* po = (unsigned short*)((char*)d_ws + fixed_end);
  float* pml = (float*)(po + (size_t)BATCH * 32 * MAXCH * 64 * 64);
  int CHUNK = SEQ / MAXCH;
  const int NACT = 32 + 16 * (MAXCH - 1);    // active (qt,ch) pairs per batch
  attn_partial<<<NACT * BATCH, 256, 0, stream>>>(qws, kws, vtws, po, pml,
                                                 MAXCH, CHUNK);
  attn_combine<<<64 * BATCH, 256, 0, stream>>>(po, pml, out, MAXCH, CHUNK);
}

// Round 22
// 53.350 us; speedup vs baseline: 1.0042x; 1.0042x over previous
//
#include <hip/hip_runtime.h>
#include <hip/hip_bf16.h>

// ---------------------------------------------------------------------------
// SingleHead attention: q=xWq, k=xWk, v=xWv; causal softmax(qk^T/sqrt(64)) v
// B=8, T=2048, C=1024, D=64.  Output fp32 [B,T,64].
//
//   k0: WT bf16 transpose of [Wq|Wk|Wv] (192x1024), pre-swizzled tile layout,
//       0.125*log2(e) folded into q columns.  LDS-transpose, coalesced 16B
//       writes.
//   k1: QKV projection GEMM, 32 tok x 192 ft block, K-step 64, dbuf LDS,
//       x reg-prefetch depth 2, WT via global_load_lds, XCD-affine grid
//   k2: split-K flash attn partials, swapped QK^T, K/V LDS dbuf,
//       id%8==batch XCD mapping; po partials in BF16; MAXCH=8
//   k3: combine partials, 512 blocks (2 per q-tile, 32 rows each),
//       static unroll 8, bf16 po reads, fp32 accumulate
//
//   FINAL (21 rounds).  Measured landscape: MAXCH {4,8,16} -> {60.4, 53.7,
//   56.6}; fused-combine via threadfence = +160us (cross-XCD L2 drain);
//   nontemporal po = +4.5us; direct-L2 K/V = +25us; 8-wave block = +2us;
//   triple-buffer+counted-vmcnt = +5us; compacted grid = neutral.
//   Champion: 53.33us (161.6us at round 1 -> 3.0x).
// ---------------------------------------------------------------------------

typedef __attribute__((ext_vector_type(8))) short short8;   // 8 x bf16 frag
typedef __attribute__((ext_vector_type(4))) float f32x4;    // C/D frag

#define MFMA16(a, b, c) __builtin_amdgcn_mfma_f32_16x16x32_bf16((a), (b), (c), 0, 0, 0)

__device__ __forceinline__ unsigned short f2bf(float f) {
  unsigned int u = __builtin_bit_cast(unsigned int, f);
  unsigned int r = 0x7fffu + ((u >> 16) & 1u);
  return (unsigned short)((u + r) >> 16);
}
__device__ __forceinline__ float bf2f(unsigned short h) {
  unsigned int u = ((unsigned int)h) << 16;
  return __builtin_bit_cast(float, u);
}

#define BATCH 8
#define SEQ   2048
#define CDIM  1024
#define DDIM  64
#define NTOK  (BATCH * SEQ)   // 16384
#define LOG2E 1.44269504f

// ---------------------------------------------------------------------------
// Kernel 0: WT pre-swizzled tiles via LDS transpose.
//   Grid 48 = 3 W x 16 k-steps; block 256.  Tile = 64 k x 64 c fp32.
//   Layout: WT[step*12288 + row*64 + ((col>>3)^(row&7))*8 + (col&7)]
// ---------------------------------------------------------------------------
__global__ __launch_bounds__(256) void wt_kernel(const float* __restrict__ Wq,
                                                 const float* __restrict__ Wk,
                                                 const float* __restrict__ Wv,
                                                 unsigned short* __restrict__ WT) {
  __shared__ float tile[64 * 68];                 // [k_local][c], stride 68
  const int wi   = blockIdx.x >> 4;               // 0..2
  const int step = blockIdx.x & 15;               // 0..15
  const int tid  = threadIdx.x;
  const float* W = (wi == 0) ? Wq : ((wi == 1) ? Wk : Wv);
  const float scale = (wi == 0) ? 0.125f * LOG2E : 1.0f;

#pragma unroll
  for (int j = 0; j < 4; ++j) {
    int r  = j * 16 + (tid >> 4);                 // k_local 0..63
    int cq = (tid & 15) * 4;                      // col quad
    f32x4 v = *reinterpret_cast<const f32x4*>(W + (size_t)(step * 64 + r) * 64 + cq);
    v *= scale;
    *reinterpret_cast<f32x4*>(&tile[r * 68 + cq]) = v;
  }
  __syncthreads();

#pragma unroll
  for (int u = 0; u < 2; ++u) {
    int p  = tid * 2 + u;                         // chunk id 0..511
    int c  = p >> 3;                              // output row within W (0..63)
    int j  = p & 7;                               // output chunk
    int k0 = (j ^ (c & 7)) * 8;                   // source col base
    short8 h;
#pragma unroll
    for (int e = 0; e < 8; ++e)
      h[e] = (short)f2bf(tile[(k0 + e) * 68 + c]);
    *reinterpret_cast<short8*>(
        WT + (size_t)step * 12288 + (size_t)(wi * 64 + c) * 64 + j * 8) = h;
  }
}

// ---------------------------------------------------------------------------
// Kernel 1: fused QKV projection GEMM.
//   512 thr = 8 waves (2M x 4N). Block tile 32 tok x 192 ft. K-step 64.
//   x register-prefetched 2 steps ahead; WT LDS-dbuf via global_load_lds.
//   XCD-affine: n0 = (id&7)*2048 + (id>>3)*32  (id%8 == batch == XCD).
// ---------------------------------------------------------------------------
__global__ __launch_bounds__(512) void proj_kernel(const float* __restrict__ x,
                                                   const unsigned short* __restrict__ WT,
                                                   unsigned short* __restrict__ qws,
                                                   unsigned short* __restrict__ kws,
                                                   unsigned short* __restrict__ vtws) {
  __shared__ __align__(16) unsigned short xs[2][32 * 64];    // 4KB each
  __shared__ __align__(16) unsigned short wl[2][192 * 64];   // 24KB each

  const int tid  = threadIdx.x;
  const int lane = tid & 63;
  const int w    = tid >> 6;       // 0..7
  const int wm   = w & 1;          // M half (16 tok)
  const int wn   = w >> 1;         // N quarter (48 ft)
  const int c16  = lane & 15;
  const int hi   = lane >> 4;
  const int id   = blockIdx.x;
  const int n0   = (id & 7) * SEQ + (id >> 3) * 32;   // XCD-affine token base
  const bool xldr = (tid < 256);
  const int trow = (tid >> 3) & 31;  // 0..31 (x staging row, tid<256)
  const int kch  = tid & 7;          // 0..7  (x staging 16B chunk)

  f32x4 acc[3];
#pragma unroll
  for (int ct = 0; ct < 3; ++ct) acc[ct] = (f32x4){0.f, 0.f, 0.f, 0.f};

  const float* xbase = x + (size_t)(n0 + trow) * CDIM + kch * 8;
  const int xsw = trow * 64 + ((kch ^ (trow & 7)) * 8);   // swizzled x slot

  const unsigned short* wsrc = WT + (size_t)w * 1536 + (size_t)lane * 8;
  auto stage_wt = [&](int step, int bufi) {
    const unsigned short* s = wsrc + (size_t)step * 12288;
    unsigned short* d = &wl[bufi][w * 1536];
#pragma unroll
    for (int j = 0; j < 3; ++j)
      __builtin_amdgcn_global_load_lds(
          (const __attribute__((address_space(1))) void*)(s + j * 512),
          (__attribute__((address_space(3))) void*)(d + j * 512), 16, 0, 0);
  };
  auto xstore = [&](f32x4 a, f32x4 b, int bufi) {
    short8 h;
#pragma unroll
    for (int j = 0; j < 4; ++j) { h[j] = (short)f2bf(a[j]); h[4 + j] = (short)f2bf(b[j]); }
    *reinterpret_cast<short8*>(&xs[bufi][xsw]) = h;
  };

  // ---- prologue ----
  f32x4 xa1 = {0,0,0,0}, xb1 = xa1, xa2 = xa1, xb2 = xa1;
  if (xldr) {
    f32x4 a0 = *reinterpret_cast<const f32x4*>(xbase);
    f32x4 b0 = *reinterpret_cast<const f32x4*>(xbase + 4);
    xstore(a0, b0, 0);
    xa1 = *reinterpret_cast<const f32x4*>(xbase + 64);
    xb1 = *reinterpret_cast<const f32x4*>(xbase + 64 + 4);
  }
  stage_wt(0, 0);
  __syncthreads();

  int cur = 0;
  for (int st = 0; st < 16; ++st) {
    if (st + 2 < 16 && xldr) {
      xa2 = *reinterpret_cast<const f32x4*>(xbase + (st + 2) * 64);
      xb2 = *reinterpret_cast<const f32x4*>(xbase + (st + 2) * 64 + 4);
    }
    if (st + 1 < 16) stage_wt(st + 1, cur ^ 1);

    // ---- compute on cur ----
    short8 bfrag[2];
    {
      int r = wm * 16 + c16;
#pragma unroll
      for (int f = 0; f < 2; ++f)
        bfrag[f] = *reinterpret_cast<const short8*>(
            &xs[cur][r * 64 + (((f * 4 + hi) ^ (r & 7)) * 8)]);
    }
#pragma unroll
    for (int ct = 0; ct < 3; ++ct) {
      int ra = (wn * 3 + ct) * 16 + c16;
#pragma unroll
      for (int f = 0; f < 2; ++f) {
        short8 af = *reinterpret_cast<const short8*>(
            &wl[cur][ra * 64 + (((f * 4 + hi) ^ (ra & 7)) * 8)]);
        acc[ct] = MFMA16(af, bfrag[f], acc[ct]);
      }
    }

    if (st + 1 < 16 && xldr) xstore(xa1, xb1, cur ^ 1);
    __syncthreads();
    xa1 = xa2; xb1 = xb2;
    cur ^= 1;
  }

  // ---- epilogue: lane holds D[feat = (wn*3+ct)*16+hi*4+r][token] ----
  {
    const int token = n0 + wm * 16 + c16;
    const int b = token >> 11;
    const int t = token & 2047;
#pragma unroll
    for (int ct = 0; ct < 3; ++ct) {
      int cg = (wn * 3 + ct) * 16 + hi * 4;
      unsigned short h[4];
#pragma unroll
      for (int r = 0; r < 4; ++r) h[r] = f2bf(acc[ct][r]);
      if (cg < 64) {
        *reinterpret_cast<ushort4*>(qws + (size_t)token * DDIM + cg) =
            make_ushort4(h[0], h[1], h[2], h[3]);
      } else if (cg < 128) {
        *reinterpret_cast<ushort4*>(kws + (size_t)token * DDIM + (cg - 64)) =
            make_ushort4(h[0], h[1], h[2], h[3]);
      } else {
        int cv = cg - 128;
#pragma unroll
        for (int r = 0; r < 4; ++r)
          vtws[(size_t)(b * DDIM + cv + r) * SEQ + t] = h[r];
      }
    }
  }
}

// ---------------------------------------------------------------------------
// Kernel 2: split-K flash attention partials, swapped-QK^T, K/V dbuf.
//   1D grid, id = b + 8*(qt + 32*ch); XCD(id%8) == batch b; proj wrote
//   batch b's K/V/q into XCD b's L2 -> staging reads are L2-LOCAL.
//   256 thr = 4 waves; wave = 16 q rows; lane owns q = qr0 + (lane&15).
//   P^T per wave in chunk-major LDS.  LDS = 40KB.  po partials BF16.
// ---------------------------------------------------------------------------
__global__ __launch_bounds__(256) void attn_partial(const unsigned short* __restrict__ qws,
                                                    const unsigned short* __restrict__ kws,
                                                    const unsigned short* __restrict__ vtws,
                                                    unsigned short* __restrict__ po,
                                                    float* __restrict__ pml,
                                                    int MAXCH, int CHUNK) {
  __shared__ __align__(16) unsigned short kt[2][64 * 64];   // K tile  [kv][d]
  __shared__ __align__(16) unsigned short vt[2][64 * 64];   // V^T tile [dv][kv]
  __shared__ __align__(16) unsigned short pt[4][1024];      // P^T chunk-major

  const int id = blockIdx.x;
  const int b  = id & 7;
  const int qt = (id >> 3) & 31;
  const int ch = id >> 8;

  const int kv_end = qt * 64 + 64;
  const int kv0_ch = ch * CHUNK;
  if (kv0_ch >= kv_end) return;
  const int block_lim = min(kv0_ch + CHUNK, kv_end);
  const int nt = (block_lim - kv0_ch + 63) >> 6;

  const int tid  = threadIdx.x;
  const int lane = tid & 63;
  const int w    = tid >> 6;
  const int c    = lane & 15;
  const int hi   = lane >> 4;
  const int qr0  = qt * 64 + w * 16;
  const int q    = qr0 + c;            // this lane's q row
  const int kv_last = qr0 + 15;        // wave causal limit

  const unsigned short* qb = qws + (size_t)b * SEQ * DDIM;
  short8 aq0 = *reinterpret_cast<const short8*>(qb + (size_t)q * DDIM + hi * 8);
  short8 aq1 = *reinterpret_cast<const short8*>(qb + (size_t)q * DDIM + 32 + hi * 8);

  float m = -INFINITY, l = 0.f;
  f32x4 o[4];
#pragma unroll
  for (int dn = 0; dn < 4; ++dn) o[dn] = (f32x4){0.f, 0.f, 0.f, 0.f};

  unsigned short* pwv = pt[w];
  const unsigned short* kb = kws + (size_t)b * SEQ * DDIM;
  const unsigned short* vb = vtws + (size_t)b * DDIM * SEQ;

  auto stage_kv = [&](int bufi, int kv0) {   // 4 vm ops per wave
#pragma unroll
    for (int j = 0; j < 2; ++j) {
      int p   = w * 128 + j * 64 + lane;   // 16B chunk index 0..511
      int row = p >> 3;
      int chk = (p & 7) ^ (row & 7);
      __builtin_amdgcn_global_load_lds(
          (const __attribute__((address_space(1))) void*)(kb + (size_t)(kv0 + row) * DDIM + chk * 8),
          (__attribute__((address_space(3))) void*)(&kt[bufi][w * 1024 + j * 512]), 16, 0, 0);
      __builtin_amdgcn_global_load_lds(
          (const __attribute__((address_space(1))) void*)(vb + (size_t)row * SEQ + kv0 + chk * 8),
          (__attribute__((address_space(3))) void*)(&vt[bufi][w * 1024 + j * 512]), 16, 0, 0);
    }
  };

  // ---- prologue ----
  stage_kv(0, kv0_ch);
  asm volatile("s_waitcnt vmcnt(0)" ::: "memory");
  __builtin_amdgcn_s_barrier();

  int cur = 0;
  for (int t = 0; t < nt; ++t) {
    const int kv0 = kv0_ch + t * 64;
    if (t + 1 < nt) stage_kv(cur ^ 1, kv0 + 64);   // issue-early, drain at end

    if (kv0 <= kv_last) {
      // ---- S^T = K q^T : lane holds S^T[kv = n*16+hi*4+r][q=c] ----
      f32x4 s[4];
#pragma unroll
      for (int n = 0; n < 4; ++n) {
        if (kv0 + n * 16 > kv_last) {
          s[n] = (f32x4){-INFINITY, -INFINITY, -INFINITY, -INFINITY};
          continue;
        }
        const unsigned short* kr = &kt[cur][(n * 16 + c) * 64];
        short8 ka0 = *reinterpret_cast<const short8*>(kr + ((hi ^ (c & 7)) * 8));
        short8 ka1 = *reinterpret_cast<const short8*>(kr + (((4 + hi) ^ (c & 7)) * 8));
        f32x4 z = (f32x4){0.f, 0.f, 0.f, 0.f};
        z = MFMA16(ka0, aq0, z);
        s[n] = MFMA16(ka1, aq1, z);
      }

      // ---- causal mask (near diagonal only) ----
      if (kv0 + 63 > qr0) {
#pragma unroll
        for (int n = 0; n < 4; ++n)
#pragma unroll
          for (int r = 0; r < 4; ++r)
            if (kv0 + n * 16 + hi * 4 + r > q) s[n][r] = -INFINITY;
      }

      // ---- online softmax (exp2 domain; state lane-local) ----
      float mx = -INFINITY;
#pragma unroll
      for (int n = 0; n < 4; ++n)
        mx = fmaxf(mx, fmaxf(fmaxf(s[n][0], s[n][1]), fmaxf(s[n][2], s[n][3])));
      mx = fmaxf(mx, __shfl_xor(mx, 16, 64));
      mx = fmaxf(mx, __shfl_xor(mx, 32, 64));

      float nm = fmaxf(m, mx);
      float sc = __builtin_exp2f(m - nm);
      m = nm;

      // ---- P = exp2(S - nm); write P^T chunk-major (4 x ds_write_b64) ----
      float ssum = 0.f;
#pragma unroll
      for (int n = 0; n < 4; ++n) {
        float pv0 = __builtin_exp2f(s[n][0] - nm);
        float pv1 = __builtin_exp2f(s[n][1] - nm);
        float pv2 = __builtin_exp2f(s[n][2] - nm);
        float pv3 = __builtin_exp2f(s[n][3] - nm);
        ssum += (pv0 + pv1) + (pv2 + pv3);
        ushort4 h4 = make_ushort4(f2bf(pv0), f2bf(pv1), f2bf(pv2), f2bf(pv3));
        *reinterpret_cast<ushort4*>(
            pwv + (2 * n + (hi >> 1)) * 128 + c * 8 + (hi & 1) * 4) = h4;
      }
      ssum += __shfl_xor(ssum, 16, 64);
      ssum += __shfl_xor(ssum, 32, 64);
      l = l * sc + ssum;

#pragma unroll
      for (int dn = 0; dn < 4; ++dn) o[dn] *= sc;

      // ---- O^T += V^T P^T  (bp: 1 x ds_read_b128 per f) ----
      const int nf = (kv0 + 32 <= kv_last) ? 2 : 1;
      for (int f = 0; f < nf; ++f) {
        short8 bp = *reinterpret_cast<const short8*>(pwv + (f * 4 + hi) * 128 + c * 8);
#pragma unroll
        for (int dn = 0; dn < 4; ++dn) {
          const unsigned short* vr = &vt[cur][(dn * 16 + c) * 64];
          short8 va = *reinterpret_cast<const short8*>(vr + (((f * 4 + hi) ^ (c & 7)) * 8));
          o[dn] = MFMA16(va, bp, o[dn]);
        }
      }
    }

    if (t + 1 < nt) {
      asm volatile("s_waitcnt vmcnt(0)" ::: "memory");   // next tile staged
      __builtin_amdgcn_s_barrier();
    }
    cur ^= 1;
  }

  // ---- write partials (BF16): po [q-in-tile][dv], dv = dn*16+hi*4+r ----
  unsigned short* pob =
      po + (((size_t)(b * 32 + qt) * MAXCH + ch) * 64 + w * 16 + c) * 64 + hi * 4;
#pragma unroll
  for (int dn = 0; dn < 4; ++dn) {
    ushort4 h4 = make_ushort4(f2bf(o[dn][0]), f2bf(o[dn][1]),
                              f2bf(o[dn][2]), f2bf(o[dn][3]));
    *reinterpret_cast<ushort4*>(pob + dn * 16) = h4;
  }

  if (hi == 0) {
    *reinterpret_cast<float2*>(
        pml + (((size_t)(b * 32 + qt) * MAXCH + ch) * 64 + w * 16 + c) * 2) =
        make_float2(m, l);
  }
}

// ---------------------------------------------------------------------------
// Kernel 3: combine partials.  512 blocks = 2 per (b,qt), 32 rows each;
//   id%8 = batch (XCD-local po reads).  256 thr; 8 thr/row, one short8/chunk.
// ---------------------------------------------------------------------------
__global__ __launch_bounds__(256) void attn_combine(const unsigned short* __restrict__ po,
                                                    const float* __restrict__ pml,
                                                    float* __restrict__ out,
                                                    int MAXCH, int CHUNK) {
  const int id   = blockIdx.x;
  const int b    = id & 7;
  const int q2   = id >> 3;            // 0..63
  const int qt   = q2 >> 1;
  const int half = q2 & 1;
  const int tid  = threadIdx.x;
  const int row  = half * 32 + (tid >> 3);   // 0..63 within tile
  const int g    = tid & 7;                  // 8-feature group
  const int nch  = min((qt * 64 + 64 + CHUNK - 1) / CHUNK, MAXCH);

  const size_t base = (size_t)(b * 32 + qt) * MAXCH;

  float mv0 = -INFINITY, mv1 = -INFINITY, mv2 = -INFINITY, mv3 = -INFINITY;
  float mv4 = -INFINITY, mv5 = -INFINITY, mv6 = -INFINITY, mv7 = -INFINITY;
  float lv0 = 0, lv1 = 0, lv2 = 0, lv3 = 0, lv4 = 0, lv5 = 0, lv6 = 0, lv7 = 0;
#define LOADML(i) if (i < nch) { \
    float2 t = *reinterpret_cast<const float2*>(pml + (base + i) * 128 + row * 2); \
    mv##i = t.x; lv##i = t.y; }
  LOADML(0) LOADML(1) LOADML(2) LOADML(3) LOADML(4) LOADML(5) LOADML(6) LOADML(7)
#undef LOADML

  float M = fmaxf(fmaxf(fmaxf(mv0, mv1), fmaxf(mv2, mv3)),
                  fmaxf(fmaxf(mv4, mv5), fmaxf(mv6, mv7)));

  float L = 0.f;
  f32x4 a0 = {0.f,0.f,0.f,0.f}, a1 = a0;
#define ACC(i) if (i < nch) { \
    float wgt = __builtin_exp2f(mv##i - M); \
    L += wgt * lv##i; \
    const unsigned short* p = po + (base + i) * 4096 + row * 64 + g * 8; \
    short8 v0 = *reinterpret_cast<const short8*>(p); \
    f32x4 t0, t1; \
    for (int j = 0; j < 4; ++j) { \
      t0[j] = bf2f((unsigned short)v0[j]); \
      t1[j] = bf2f((unsigned short)v0[4 + j]); \
    } \
    a0 += wgt * t0; a1 += wgt * t1; }
  ACC(0) ACC(1) ACC(2) ACC(3) ACC(4) ACC(5) ACC(6) ACC(7)
#undef ACC

  float invL = 1.f / L;
  float* ob = out + ((size_t)b * SEQ + qt * 64 + row) * 64 + g * 8;
  *reinterpret_cast<f32x4*>(ob)     = a0 * invL;
  *reinterpret_cast<f32x4*>(ob + 4) = a1 * invL;
}

// ---------------------------------------------------------------------------
extern "C" void kernel_launch(void* const* d_in, const int* in_sizes, int n_in,
                              void* d_out, int out_size, void* d_ws, size_t ws_size,
                              hipStream_t stream) {
  const float* x  = (const float*)d_in[0];
  const float* Wq = (const float*)d_in[1];
  const float* Wk = (const float*)d_in[2];
  const float* Wv = (const float*)d_in[3];
  float* out = (float*)d_out;

  unsigned short* qws  = (unsigned short*)d_ws;            // 2MB
  unsigned short* kws  = qws + (size_t)NTOK * DDIM;        // 2MB
  unsigned short* vtws = kws + (size_t)NTOK * DDIM;        // 2MB
  unsigned short* WT   = vtws + (size_t)NTOK * DDIM;       // 384KB
  size_t fixed_end = (size_t)NTOK * DDIM * 3 * 2 + 192 * 1024 * 2;

  int MAXCH = 1;
  {
    const int cand[4] = {8, 4, 2, 1};
    for (int i = 0; i < 4; ++i) {
      size_t need = fixed_end +
                    (size_t)cand[i] * (8ull * 32 * 64 * 64 * 2 + 8ull * 32 * 64 * 2 * 4);
      if (need <= ws_size) { MAXCH = cand[i]; break; }
    }
  }

  wt_kernel<<<48, 256, 0, stream>>>(Wq, Wk, Wv, WT);
  proj_kernel<<<NTOK / 32, 512, 0, stream>>>(x, WT, qws, kws, vtws);

  unsigned short* po = (unsigned short*)((char*)d_ws + fixed_end);
  float* pml = (float*)(po + (size_t)BATCH * 32 * MAXCH * 64 * 64);
  int CHUNK = SEQ / MAXCH;
  attn_partial<<<32 * MAXCH * BATCH, 256, 0, stream>>>(qws, kws, vtws, po, pml,
                                                       MAXCH, CHUNK);
  attn_combine<<<64 * BATCH, 256, 0, stream>>>(po, pml, out, MAXCH, CHUNK);
}

// Round 23
// 53.262 us; speedup vs baseline: 1.0059x; 1.0017x over previous
//
#include <hip/hip_runtime.h>
#include <hip/hip_bf16.h>

// ---------------------------------------------------------------------------
// SingleHead attention: q=xWq, k=xWk, v=xWv; causal softmax(qk^T/sqrt(64)) v
// B=8, T=2048, C=1024, D=64.  Output fp32 [B,T,64].
//
//   k0: WT bf16 transpose of [Wq|Wk|Wv] (192x1024), pre-swizzled tile layout,
//       0.125*log2(e) folded into q columns.  LDS-transpose, coalesced 16B
//       writes.
//   k1: QKV projection GEMM, 32 tok x 192 ft block, K-step 64, dbuf LDS,
//       x reg-prefetch depth 2, WT via global_load_lds, XCD-affine grid
//   k2: split-K flash attn partials, swapped QK^T, K/V LDS dbuf,
//       id%8==batch XCD mapping; po partials in BF16; MAXCH=8
//   k3: combine partials, 512 blocks (2 per q-tile, 32 rows each),
//       static unroll 8, bf16 po reads, fp32 accumulate
//
//   CONVERGED (22 rounds, 7x reproduced at 53.3-53.9us).  Ledger:
//   MAXCH {4,8,16} -> {60.4, 53.7, 56.6}; fused-combine threadfence = +160us
//   (cross-XCD L2 drain); nontemporal po = +4.5us; direct-L2 K/V = +25us;
//   8-wave block = +2us; triple-buffer+counted-vmcnt = +5us; compacted
//   grid = neutral.  161.6us (round 1) -> 53.3us.
// ---------------------------------------------------------------------------

typedef __attribute__((ext_vector_type(8))) short short8;   // 8 x bf16 frag
typedef __attribute__((ext_vector_type(4))) float f32x4;    // C/D frag

#define MFMA16(a, b, c) __builtin_amdgcn_mfma_f32_16x16x32_bf16((a), (b), (c), 0, 0, 0)

__device__ __forceinline__ unsigned short f2bf(float f) {
  unsigned int u = __builtin_bit_cast(unsigned int, f);
  unsigned int r = 0x7fffu + ((u >> 16) & 1u);
  return (unsigned short)((u + r) >> 16);
}
__device__ __forceinline__ float bf2f(unsigned short h) {
  unsigned int u = ((unsigned int)h) << 16;
  return __builtin_bit_cast(float, u);
}

#define BATCH 8
#define SEQ   2048
#define CDIM  1024
#define DDIM  64
#define NTOK  (BATCH * SEQ)   // 16384
#define LOG2E 1.44269504f

// ---------------------------------------------------------------------------
// Kernel 0: WT pre-swizzled tiles via LDS transpose.
//   Grid 48 = 3 W x 16 k-steps; block 256.  Tile = 64 k x 64 c fp32.
//   Layout: WT[step*12288 + row*64 + ((col>>3)^(row&7))*8 + (col&7)]
// ---------------------------------------------------------------------------
__global__ __launch_bounds__(256) void wt_kernel(const float* __restrict__ Wq,
                                                 const float* __restrict__ Wk,
                                                 const float* __restrict__ Wv,
                                                 unsigned short* __restrict__ WT) {
  __shared__ float tile[64 * 68];                 // [k_local][c], stride 68
  const int wi   = blockIdx.x >> 4;               // 0..2
  const int step = blockIdx.x & 15;               // 0..15
  const int tid  = threadIdx.x;
  const float* W = (wi == 0) ? Wq : ((wi == 1) ? Wk : Wv);
  const float scale = (wi == 0) ? 0.125f * LOG2E : 1.0f;

#pragma unroll
  for (int j = 0; j < 4; ++j) {
    int r  = j * 16 + (tid >> 4);                 // k_local 0..63
    int cq = (tid & 15) * 4;                      // col quad
    f32x4 v = *reinterpret_cast<const f32x4*>(W + (size_t)(step * 64 + r) * 64 + cq);
    v *= scale;
    *reinterpret_cast<f32x4*>(&tile[r * 68 + cq]) = v;
  }
  __syncthreads();

#pragma unroll
  for (int u = 0; u < 2; ++u) {
    int p  = tid * 2 + u;                         // chunk id 0..511
    int c  = p >> 3;                              // output row within W (0..63)
    int j  = p & 7;                               // output chunk
    int k0 = (j ^ (c & 7)) * 8;                   // source col base
    short8 h;
#pragma unroll
    for (int e = 0; e < 8; ++e)
      h[e] = (short)f2bf(tile[(k0 + e) * 68 + c]);
    *reinterpret_cast<short8*>(
        WT + (size_t)step * 12288 + (size_t)(wi * 64 + c) * 64 + j * 8) = h;
  }
}

// ---------------------------------------------------------------------------
// Kernel 1: fused QKV projection GEMM.
//   512 thr = 8 waves (2M x 4N). Block tile 32 tok x 192 ft. K-step 64.
//   x register-prefetched 2 steps ahead; WT LDS-dbuf via global_load_lds.
//   XCD-affine: n0 = (id&7)*2048 + (id>>3)*32  (id%8 == batch == XCD).
// ---------------------------------------------------------------------------
__global__ __launch_bounds__(512) void proj_kernel(const float* __restrict__ x,
                                                   const unsigned short* __restrict__ WT,
                                                   unsigned short* __restrict__ qws,
                                                   unsigned short* __restrict__ kws,
                                                   unsigned short* __restrict__ vtws) {
  __shared__ __align__(16) unsigned short xs[2][32 * 64];    // 4KB each
  __shared__ __align__(16) unsigned short wl[2][192 * 64];   // 24KB each

  const int tid  = threadIdx.x;
  const int lane = tid & 63;
  const int w    = tid >> 6;       // 0..7
  const int wm   = w & 1;          // M half (16 tok)
  const int wn   = w >> 1;         // N quarter (48 ft)
  const int c16  = lane & 15;
  const int hi   = lane >> 4;
  const int id   = blockIdx.x;
  const int n0   = (id & 7) * SEQ + (id >> 3) * 32;   // XCD-affine token base
  const bool xldr = (tid < 256);
  const int trow = (tid >> 3) & 31;  // 0..31 (x staging row, tid<256)
  const int kch  = tid & 7;          // 0..7  (x staging 16B chunk)

  f32x4 acc[3];
#pragma unroll
  for (int ct = 0; ct < 3; ++ct) acc[ct] = (f32x4){0.f, 0.f, 0.f, 0.f};

  const float* xbase = x + (size_t)(n0 + trow) * CDIM + kch * 8;
  const int xsw = trow * 64 + ((kch ^ (trow & 7)) * 8);   // swizzled x slot

  const unsigned short* wsrc = WT + (size_t)w * 1536 + (size_t)lane * 8;
  auto stage_wt = [&](int step, int bufi) {
    const unsigned short* s = wsrc + (size_t)step * 12288;
    unsigned short* d = &wl[bufi][w * 1536];
#pragma unroll
    for (int j = 0; j < 3; ++j)
      __builtin_amdgcn_global_load_lds(
          (const __attribute__((address_space(1))) void*)(s + j * 512),
          (__attribute__((address_space(3))) void*)(d + j * 512), 16, 0, 0);
  };
  auto xstore = [&](f32x4 a, f32x4 b, int bufi) {
    short8 h;
#pragma unroll
    for (int j = 0; j < 4; ++j) { h[j] = (short)f2bf(a[j]); h[4 + j] = (short)f2bf(b[j]); }
    *reinterpret_cast<short8*>(&xs[bufi][xsw]) = h;
  };

  // ---- prologue ----
  f32x4 xa1 = {0,0,0,0}, xb1 = xa1, xa2 = xa1, xb2 = xa1;
  if (xldr) {
    f32x4 a0 = *reinterpret_cast<const f32x4*>(xbase);
    f32x4 b0 = *reinterpret_cast<const f32x4*>(xbase + 4);
    xstore(a0, b0, 0);
    xa1 = *reinterpret_cast<const f32x4*>(xbase + 64);
    xb1 = *reinterpret_cast<const f32x4*>(xbase + 64 + 4);
  }
  stage_wt(0, 0);
  __syncthreads();

  int cur = 0;
  for (int st = 0; st < 16; ++st) {
    if (st + 2 < 16 && xldr) {
      xa2 = *reinterpret_cast<const f32x4*>(xbase + (st + 2) * 64);
      xb2 = *reinterpret_cast<const f32x4*>(xbase + (st + 2) * 64 + 4);
    }
    if (st + 1 < 16) stage_wt(st + 1, cur ^ 1);

    // ---- compute on cur ----
    short8 bfrag[2];
    {
      int r = wm * 16 + c16;
#pragma unroll
      for (int f = 0; f < 2; ++f)
        bfrag[f] = *reinterpret_cast<const short8*>(
            &xs[cur][r * 64 + (((f * 4 + hi) ^ (r & 7)) * 8)]);
    }
#pragma unroll
    for (int ct = 0; ct < 3; ++ct) {
      int ra = (wn * 3 + ct) * 16 + c16;
#pragma unroll
      for (int f = 0; f < 2; ++f) {
        short8 af = *reinterpret_cast<const short8*>(
            &wl[cur][ra * 64 + (((f * 4 + hi) ^ (ra & 7)) * 8)]);
        acc[ct] = MFMA16(af, bfrag[f], acc[ct]);
      }
    }

    if (st + 1 < 16 && xldr) xstore(xa1, xb1, cur ^ 1);
    __syncthreads();
    xa1 = xa2; xb1 = xb2;
    cur ^= 1;
  }

  // ---- epilogue: lane holds D[feat = (wn*3+ct)*16+hi*4+r][token] ----
  {
    const int token = n0 + wm * 16 + c16;
    const int b = token >> 11;
    const int t = token & 2047;
#pragma unroll
    for (int ct = 0; ct < 3; ++ct) {
      int cg = (wn * 3 + ct) * 16 + hi * 4;
      unsigned short h[4];
#pragma unroll
      for (int r = 0; r < 4; ++r) h[r] = f2bf(acc[ct][r]);
      if (cg < 64) {
        *reinterpret_cast<ushort4*>(qws + (size_t)token * DDIM + cg) =
            make_ushort4(h[0], h[1], h[2], h[3]);
      } else if (cg < 128) {
        *reinterpret_cast<ushort4*>(kws + (size_t)token * DDIM + (cg - 64)) =
            make_ushort4(h[0], h[1], h[2], h[3]);
      } else {
        int cv = cg - 128;
#pragma unroll
        for (int r = 0; r < 4; ++r)
          vtws[(size_t)(b * DDIM + cv + r) * SEQ + t] = h[r];
      }
    }
  }
}

// ---------------------------------------------------------------------------
// Kernel 2: split-K flash attention partials, swapped-QK^T, K/V dbuf.
//   1D grid, id = b + 8*(qt + 32*ch); XCD(id%8) == batch b; proj wrote
//   batch b's K/V/q into XCD b's L2 -> staging reads are L2-LOCAL.
//   256 thr = 4 waves; wave = 16 q rows; lane owns q = qr0 + (lane&15).
//   P^T per wave in chunk-major LDS.  LDS = 40KB.  po partials BF16.
// ---------------------------------------------------------------------------
__global__ __launch_bounds__(256) void attn_partial(const unsigned short* __restrict__ qws,
                                                    const unsigned short* __restrict__ kws,
                                                    const unsigned short* __restrict__ vtws,
                                                    unsigned short* __restrict__ po,
                                                    float* __restrict__ pml,
                                                    int MAXCH, int CHUNK) {
  __shared__ __align__(16) unsigned short kt[2][64 * 64];   // K tile  [kv][d]
  __shared__ __align__(16) unsigned short vt[2][64 * 64];   // V^T tile [dv][kv]
  __shared__ __align__(16) unsigned short pt[4][1024];      // P^T chunk-major

  const int id = blockIdx.x;
  const int b  = id & 7;
  const int qt = (id >> 3) & 31;
  const int ch = id >> 8;

  const int kv_end = qt * 64 + 64;
  const int kv0_ch = ch * CHUNK;
  if (kv0_ch >= kv_end) return;
  const int block_lim = min(kv0_ch + CHUNK, kv_end);
  const int nt = (block_lim - kv0_ch + 63) >> 6;

  const int tid  = threadIdx.x;
  const int lane = tid & 63;
  const int w    = tid >> 6;
  const int c    = lane & 15;
  const int hi   = lane >> 4;
  const int qr0  = qt * 64 + w * 16;
  const int q    = qr0 + c;            // this lane's q row
  const int kv_last = qr0 + 15;        // wave causal limit

  const unsigned short* qb = qws + (size_t)b * SEQ * DDIM;
  short8 aq0 = *reinterpret_cast<const short8*>(qb + (size_t)q * DDIM + hi * 8);
  short8 aq1 = *reinterpret_cast<const short8*>(qb + (size_t)q * DDIM + 32 + hi * 8);

  float m = -INFINITY, l = 0.f;
  f32x4 o[4];
#pragma unroll
  for (int dn = 0; dn < 4; ++dn) o[dn] = (f32x4){0.f, 0.f, 0.f, 0.f};

  unsigned short* pwv = pt[w];
  const unsigned short* kb = kws + (size_t)b * SEQ * DDIM;
  const unsigned short* vb = vtws + (size_t)b * DDIM * SEQ;

  auto stage_kv = [&](int bufi, int kv0) {   // 4 vm ops per wave
#pragma unroll
    for (int j = 0; j < 2; ++j) {
      int p   = w * 128 + j * 64 + lane;   // 16B chunk index 0..511
      int row = p >> 3;
      int chk = (p & 7) ^ (row & 7);
      __builtin_amdgcn_global_load_lds(
          (const __attribute__((address_space(1))) void*)(kb + (size_t)(kv0 + row) * DDIM + chk * 8),
          (__attribute__((address_space(3))) void*)(&kt[bufi][w * 1024 + j * 512]), 16, 0, 0);
      __builtin_amdgcn_global_load_lds(
          (const __attribute__((address_space(1))) void*)(vb + (size_t)row * SEQ + kv0 + chk * 8),
          (__attribute__((address_space(3))) void*)(&vt[bufi][w * 1024 + j * 512]), 16, 0, 0);
    }
  };

  // ---- prologue ----
  stage_kv(0, kv0_ch);
  asm volatile("s_waitcnt vmcnt(0)" ::: "memory");
  __builtin_amdgcn_s_barrier();

  int cur = 0;
  for (int t = 0; t < nt; ++t) {
    const int kv0 = kv0_ch + t * 64;
    if (t + 1 < nt) stage_kv(cur ^ 1, kv0 + 64);   // issue-early, drain at end

    if (kv0 <= kv_last) {
      // ---- S^T = K q^T : lane holds S^T[kv = n*16+hi*4+r][q=c] ----
      f32x4 s[4];
#pragma unroll
      for (int n = 0; n < 4; ++n) {
        if (kv0 + n * 16 > kv_last) {
          s[n] = (f32x4){-INFINITY, -INFINITY, -INFINITY, -INFINITY};
          continue;
        }
        const unsigned short* kr = &kt[cur][(n * 16 + c) * 64];
        short8 ka0 = *reinterpret_cast<const short8*>(kr + ((hi ^ (c & 7)) * 8));
        short8 ka1 = *reinterpret_cast<const short8*>(kr + (((4 + hi) ^ (c & 7)) * 8));
        f32x4 z = (f32x4){0.f, 0.f, 0.f, 0.f};
        z = MFMA16(ka0, aq0, z);
        s[n] = MFMA16(ka1, aq1, z);
      }

      // ---- causal mask (near diagonal only) ----
      if (kv0 + 63 > qr0) {
#pragma unroll
        for (int n = 0; n < 4; ++n)
#pragma unroll
          for (int r = 0; r < 4; ++r)
            if (kv0 + n * 16 + hi * 4 + r > q) s[n][r] = -INFINITY;
      }

      // ---- online softmax (exp2 domain; state lane-local) ----
      float mx = -INFINITY;
#pragma unroll
      for (int n = 0; n < 4; ++n)
        mx = fmaxf(mx, fmaxf(fmaxf(s[n][0], s[n][1]), fmaxf(s[n][2], s[n][3])));
      mx = fmaxf(mx, __shfl_xor(mx, 16, 64));
      mx = fmaxf(mx, __shfl_xor(mx, 32, 64));

      float nm = fmaxf(m, mx);
      float sc = __builtin_exp2f(m - nm);
      m = nm;

      // ---- P = exp2(S - nm); write P^T chunk-major (4 x ds_write_b64) ----
      float ssum = 0.f;
#pragma unroll
      for (int n = 0; n < 4; ++n) {
        float pv0 = __builtin_exp2f(s[n][0] - nm);
        float pv1 = __builtin_exp2f(s[n][1] - nm);
        float pv2 = __builtin_exp2f(s[n][2] - nm);
        float pv3 = __builtin_exp2f(s[n][3] - nm);
        ssum += (pv0 + pv1) + (pv2 + pv3);
        ushort4 h4 = make_ushort4(f2bf(pv0), f2bf(pv1), f2bf(pv2), f2bf(pv3));
        *reinterpret_cast<ushort4*>(
            pwv + (2 * n + (hi >> 1)) * 128 + c * 8 + (hi & 1) * 4) = h4;
      }
      ssum += __shfl_xor(ssum, 16, 64);
      ssum += __shfl_xor(ssum, 32, 64);
      l = l * sc + ssum;

#pragma unroll
      for (int dn = 0; dn < 4; ++dn) o[dn] *= sc;

      // ---- O^T += V^T P^T  (bp: 1 x ds_read_b128 per f) ----
      const int nf = (kv0 + 32 <= kv_last) ? 2 : 1;
      for (int f = 0; f < nf; ++f) {
        short8 bp = *reinterpret_cast<const short8*>(pwv + (f * 4 + hi) * 128 + c * 8);
#pragma unroll
        for (int dn = 0; dn < 4; ++dn) {
          const unsigned short* vr = &vt[cur][(dn * 16 + c) * 64];
          short8 va = *reinterpret_cast<const short8*>(vr + (((f * 4 + hi) ^ (c & 7)) * 8));
          o[dn] = MFMA16(va, bp, o[dn]);
        }
      }
    }

    if (t + 1 < nt) {
      asm volatile("s_waitcnt vmcnt(0)" ::: "memory");   // next tile staged
      __builtin_amdgcn_s_barrier();
    }
    cur ^= 1;
  }

  // ---- write partials (BF16): po [q-in-tile][dv], dv = dn*16+hi*4+r ----
  unsigned short* pob =
      po + (((size_t)(b * 32 + qt) * MAXCH + ch) * 64 + w * 16 + c) * 64 + hi * 4;
#pragma unroll
  for (int dn = 0; dn < 4; ++dn) {
    ushort4 h4 = make_ushort4(f2bf(o[dn][0]), f2bf(o[dn][1]),
                              f2bf(o[dn][2]), f2bf(o[dn][3]));
    *reinterpret_cast<ushort4*>(pob + dn * 16) = h4;
  }

  if (hi == 0) {
    *reinterpret_cast<float2*>(
        pml + (((size_t)(b * 32 + qt) * MAXCH + ch) * 64 + w * 16 + c) * 2) =
        make_float2(m, l);
  }
}

// ---------------------------------------------------------------------------
// Kernel 3: combine partials.  512 blocks = 2 per (b,qt), 32 rows each;
//   id%8 = batch (XCD-local po reads).  256 thr; 8 thr/row, one short8/chunk.
// ---------------------------------------------------------------------------
__global__ __launch_bounds__(256) void attn_combine(const unsigned short* __restrict__ po,
                                                    const float* __restrict__ pml,
                                                    float* __restrict__ out,
                                                    int MAXCH, int CHUNK) {
  const int id   = blockIdx.x;
  const int b    = id & 7;
  const int q2   = id >> 3;            // 0..63
  const int qt   = q2 >> 1;
  const int half = q2 & 1;
  const int tid  = threadIdx.x;
  const int row  = half * 32 + (tid >> 3);   // 0..63 within tile
  const int g    = tid & 7;                  // 8-feature group
  const int nch  = min((qt * 64 + 64 + CHUNK - 1) / CHUNK, MAXCH);

  const size_t base = (size_t)(b * 32 + qt) * MAXCH;

  float mv0 = -INFINITY, mv1 = -INFINITY, mv2 = -INFINITY, mv3 = -INFINITY;
  float mv4 = -INFINITY, mv5 = -INFINITY, mv6 = -INFINITY, mv7 = -INFINITY;
  float lv0 = 0, lv1 = 0, lv2 = 0, lv3 = 0, lv4 = 0, lv5 = 0, lv6 = 0, lv7 = 0;
#define LOADML(i) if (i < nch) { \
    float2 t = *reinterpret_cast<const float2*>(pml + (base + i) * 128 + row * 2); \
    mv##i = t.x; lv##i = t.y; }
  LOADML(0) LOADML(1) LOADML(2) LOADML(3) LOADML(4) LOADML(5) LOADML(6) LOADML(7)
#undef LOADML

  float M = fmaxf(fmaxf(fmaxf(mv0, mv1), fmaxf(mv2, mv3)),
                  fmaxf(fmaxf(mv4, mv5), fmaxf(mv6, mv7)));

  float L = 0.f;
  f32x4 a0 = {0.f,0.f,0.f,0.f}, a1 = a0;
#define ACC(i) if (i < nch) { \
    float wgt = __builtin_exp2f(mv##i - M); \
    L += wgt * lv##i; \
    const unsigned short* p = po + (base + i) * 4096 + row * 64 + g * 8; \
    short8 v0 = *reinterpret_cast<const short8*>(p); \
    f32x4 t0, t1; \
    for (int j = 0; j < 4; ++j) { \
      t0[j] = bf2f((unsigned short)v0[j]); \
      t1[j] = bf2f((unsigned short)v0[4 + j]); \
    } \
    a0 += wgt * t0; a1 += wgt * t1; }
  ACC(0) ACC(1) ACC(2) ACC(3) ACC(4) ACC(5) ACC(6) ACC(7)
#undef ACC

  float invL = 1.f / L;
  float* ob = out + ((size_t)b * SEQ + qt * 64 + row) * 64 + g * 8;
  *reinterpret_cast<f32x4*>(ob)     = a0 * invL;
  *reinterpret_cast<f32x4*>(ob + 4) = a1 * invL;
}

// ---------------------------------------------------------------------------
extern "C" void kernel_launch(void* const* d_in, const int* in_sizes, int n_in,
                              void* d_out, int out_size, void* d_ws, size_t ws_size,
                              hipStream_t stream) {
  const float* x  = (const float*)d_in[0];
  const float* Wq = (const float*)d_in[1];
  const float* Wk = (const float*)d_in[2];
  const float* Wv = (const float*)d_in[3];
  float* out = (float*)d_out;

  unsigned short* qws  = (unsigned short*)d_ws;            // 2MB
  unsigned short* kws  = qws + (size_t)NTOK * DDIM;        // 2MB
  unsigned short* vtws = kws + (size_t)NTOK * DDIM;        // 2MB
  unsigned short* WT   = vtws + (size_t)NTOK * DDIM;       // 384KB
  size_t fixed_end = (size_t)NTOK * DDIM * 3 * 2 + 192 * 1024 * 2;

  int MAXCH = 1;
  {
    const int cand[4] = {8, 4, 2, 1};
    for (int i = 0; i < 4; ++i) {
      size_t need = fixed_end +
                    (size_t)cand[i] * (8ull * 32 * 64 * 64 * 2 + 8ull * 32 * 64 * 2 * 4);
      if (need <= ws_size) { MAXCH = cand[i]; break; }
    }
  }

  wt_kernel<<<48, 256, 0, stream>>>(Wq, Wk, Wv, WT);
  proj_kernel<<<NTOK / 32, 512, 0, stream>>>(x, WT, qws, kws, vtws);

  unsigned short* po = (unsigned short*)((char*)d_ws + fixed_end);
  float* pml = (float*)(po + (size_t)BATCH * 32 * MAXCH * 64 * 64);
  int CHUNK = SEQ / MAXCH;
  attn_partial<<<32 * MAXCH * BATCH, 256, 0, stream>>>(qws, kws, vtws, po, pml,
                                                       MAXCH, CHUNK);
  attn_combine<<<64 * BATCH, 256, 0, stream>>>(po, pml, out, MAXCH, CHUNK);
}